// Round 13
// baseline (274.542 us; speedup 1.0000x reference)
//
#include <hip/hip_runtime.h>

#define D 1024
#define NH 16
#define HD 64
#define SEQ 2048
#define BATCH 4
#define LN_EPS 1e-5f
#define LOG2E 1.44269504088896f

typedef __attribute__((ext_vector_type(8))) __bf16 bf16x8;
typedef __attribute__((ext_vector_type(4))) float f32x4;

__device__ __forceinline__ ushort f2bf(float f) {
    union { float f; uint u; } c; c.f = f;
    uint u = c.u + 0x7fffu + ((c.u >> 16) & 1u);   // RNE
    return (ushort)(u >> 16);
}

// async global->LDS DMA, 16B per lane; LDS dest = wave-uniform base + lane*16
__device__ __forceinline__ void gl_lds16(const ushort* g, ushort* lds) {
    __builtin_amdgcn_global_load_lds(
        (const __attribute__((address_space(1))) void*)g,
        (__attribute__((address_space(3))) void*)lds, 16, 0, 0);
}

// raw v_exp_f32: D = 2^S0 (cdna4_isa §3). Single VALU inst, no OCML path.
__device__ __forceinline__ float exp2_raw(float v) {
    float e;
    asm("v_exp_f32 %0, %1" : "=v"(e) : "v"(v));
    return e;
}

// ---------------------------------------------------------------------------
// prep: fused {LayerNorm rows} + {fp32->bf16 convert of 4 weight matrices}.
// LN = one wave per row (4 rows/block), pure shfl_xor butterfly — zero
// barriers, zero LDS. (Round-10 verified: −6.4us vs 4-wave version.)
// ---------------------------------------------------------------------------
__global__ __launch_bounds__(256) void prep(
    const float* __restrict__ x, const float* __restrict__ gamma,
    const float* __restrict__ beta, ushort* __restrict__ xn,
    const float* __restrict__ w0, const float* __restrict__ w1,
    const float* __restrict__ w2, const float* __restrict__ w3,
    ushort* __restrict__ wout)
{
    const int bid = blockIdx.x;
    const int tid = threadIdx.x;
    if (bid < BATCH * SEQ / 4) {
        // ---- LayerNorm: one row per wave ----
        const int wave = tid >> 6, lane = tid & 63;
        const int row = bid * 4 + wave;
        const float4* xr = (const float4*)(x + (size_t)row * D);
        float4 v[4];
        float s = 0.f;
#pragma unroll
        for (int t = 0; t < 4; ++t) {
            v[t] = xr[t * 64 + lane];
            s += (v[t].x + v[t].y) + (v[t].z + v[t].w);
        }
#pragma unroll
        for (int off = 32; off > 0; off >>= 1) s += __shfl_xor(s, off, 64);
        float mean = s * (1.0f / D);
        float ss = 0.f;
#pragma unroll
        for (int t = 0; t < 4; ++t) {
            float dx = v[t].x - mean, dy = v[t].y - mean;
            float dz = v[t].z - mean, dw = v[t].w - mean;
            ss += (dx * dx + dy * dy) + (dz * dz + dw * dw);
        }
#pragma unroll
        for (int off = 32; off > 0; off >>= 1) ss += __shfl_xor(ss, off, 64);
        float rstd = rsqrtf(ss * (1.0f / D) + LN_EPS);
        ushort4* xo = (ushort4*)(xn + (size_t)row * D);
#pragma unroll
        for (int t = 0; t < 4; ++t) {
            float4 g = ((const float4*)gamma)[t * 64 + lane];
            float4 b = ((const float4*)beta)[t * 64 + lane];
            ushort4 o;
            o.x = f2bf((v[t].x - mean) * rstd * g.x + b.x);
            o.y = f2bf((v[t].y - mean) * rstd * g.y + b.y);
            o.z = f2bf((v[t].z - mean) * rstd * g.z + b.z);
            o.w = f2bf((v[t].w - mean) * rstd * g.w + b.w);
            xo[t * 64 + lane] = o;
        }
    } else {
        // ---- weight convert ----
        const int n = D * D;
        int p = bid - BATCH * SEQ / 4;
        int sel = p >> 10;                 // 0..3
        int xblk = p & 1023;
        const float* in = sel == 0 ? w0 : (sel == 1 ? w1 : (sel == 2 ? w2 : w3));
        int i = (xblk * 256 + tid) * 4;
        float4 v = *(const float4*)(in + i);
        ushort4 o;
        o.x = f2bf(v.x); o.y = f2bf(v.y); o.z = f2bf(v.z); o.w = f2bf(v.w);
        *(ushort4*)(wout + (size_t)sel * n + i) = o;
    }
}

// ---------------------------------------------------------------------------
// GEMM (final form): 128x128 tile, BK=64, XOR-swizzled DMA staging, 2-phase
// double-buffer with a single compiler-scheduled __syncthreads per K-step.
// Round 13 = Round-12 RETRY (container failed twice; no code suspect — the
// only delta vs the verified 270.0us kernel is plain-integer grid decode).
// T1 chunked XCD swizzle on gemm_qkv: grid 1D 1536 (=8x192),
// lid = (id%8)*192 + id/8, bx = lid%24 (fastest), by = lid/24. Each XCD runs
// 8 complete by-groups; the 24 blocks sharing one 256KB A-panel execute
// back-to-back on ONE XCD -> panel stays L2-resident for all 24 uses
// (was: consecutive blockIdx round-robin'd the sharers across 8 XCDs,
// per-XCD A working set 16MB >> 4MB L2 -> FETCH 75.5MB vs 22MB ideal).
// Bijective since 1536%8==0 (ERRATA #11 satisfied); perf-only heuristic.
// ---------------------------------------------------------------------------
#define BM 128
#define BKK 64

// ---------------------------------------------------------------------------
// Fused QKV GEMM: W = stacked [Wq;Wk;Wv] = [3072][1024] bf16. Grid 1536 (1D).
// Region 0->Q, 1->K row-major bf16; region 2 -> V transposed to [B,H,D,S].
// ---------------------------------------------------------------------------
__global__ __launch_bounds__(256) void gemm_qkv(
    const ushort* __restrict__ A,    // [M,1024] bf16
    const ushort* __restrict__ W,    // [3072,1024] bf16
    const float* __restrict__ bq, const float* __restrict__ bk,
    const float* __restrict__ bv,
    ushort* __restrict__ Cq, ushort* __restrict__ Ck,
    ushort* __restrict__ CvT,
    int M, int K)
{
    __shared__ ushort As[2][BM * BKK];   // 2 x 16 KB
    __shared__ ushort Ws[2][BM * BKK];
    const int tid = threadIdx.x;
    const int lane = tid & 63;
    const int wave = tid >> 6;
    const int wr = wave >> 1, wc = wave & 1;
    // XCD-chunked decode: XCD k (id%8) gets contiguous lid chunk of 192.
    const int id0 = blockIdx.x;
    const int lid = (id0 & 7) * 192 + (id0 >> 3);
    const int bxx = lid % 24;            // n-tile, iterates fastest in chunk
    const int byy = lid / 24;            // m-tile (A-panel) — 8 per XCD
    const int m0 = byy * BM;
    const int n0g = bxx * BM;
    const int region = n0g >> 10;
    const int n0l = n0g & 1023;
    const float* bias = region == 0 ? bq : (region == 1 ? bk : bv);
    const int fr = lane & 15, quad = lane >> 4;
    const int r8 = lane >> 3, c8 = lane & 7;
    const int gc8 = c8 ^ r8;               // swizzled global chunk
    const int swf = fr & 7;

    const ushort* gA = A + (size_t)(m0 + wave * 32 + r8) * K + gc8 * 8;
    const ushort* gW = W + (size_t)(n0g + wave * 32 + r8) * K + gc8 * 8;
    const int ldso = (wave * 32) * BKK;

    f32x4 acc[4][4] = {};

    // prologue: stage tile 0 into buffer 0
#pragma unroll
    for (int t = 0; t < 4; ++t) {
        gl_lds16(gA + (size_t)t * 8 * K, &As[0][ldso + t * 8 * BKK]);
        gl_lds16(gW + (size_t)t * 8 * K, &Ws[0][ldso + t * 8 * BKK]);
    }
    __syncthreads();

    for (int k0 = 0; k0 < K; k0 += BKK) {
        const int cur = (k0 >> 6) & 1;
        if (k0 + BKK < K) {
            const int nxt = cur ^ 1;
#pragma unroll
            for (int t = 0; t < 4; ++t) {
                gl_lds16(gA + (size_t)t * 8 * K + k0 + BKK, &As[nxt][ldso + t * 8 * BKK]);
                gl_lds16(gW + (size_t)t * 8 * K + k0 + BKK, &Ws[nxt][ldso + t * 8 * BKK]);
            }
        }
#pragma unroll
        for (int kh = 0; kh < 2; ++kh) {
            bf16x8 af[4], bf[4];
            const int co = ((kh * 4 + quad) ^ swf) * 8;
#pragma unroll
            for (int i = 0; i < 4; ++i) {
                af[i] = *(const bf16x8*)&As[cur][(wr * 64 + i * 16 + fr) * BKK + co];
                bf[i] = *(const bf16x8*)&Ws[cur][(wc * 64 + i * 16 + fr) * BKK + co];
            }
#pragma unroll
            for (int i = 0; i < 4; ++i)
#pragma unroll
                for (int j = 0; j < 4; ++j)
                    acc[i][j] = __builtin_amdgcn_mfma_f32_16x16x32_bf16(af[i], bf[j], acc[i][j], 0, 0, 0);
        }
        __syncthreads();   // drains prefetch vmcnt + fragment lgkm; one barrier/K-step
    }

#pragma unroll
    for (int j = 0; j < 4; ++j) {
        int col = n0l + wc * 64 + j * 16 + fr;
        float bvl = bias[col];
#pragma unroll
        for (int i = 0; i < 4; ++i) {
#pragma unroll
            for (int r = 0; r < 4; ++r) {
                int row = m0 + wr * 64 + i * 16 + quad * 4 + r;
                ushort hv = f2bf(acc[i][j][r] + bvl);
                if (region == 0) {
                    Cq[(size_t)row * 1024 + col] = hv;
                } else if (region == 1) {
                    Ck[(size_t)row * 1024 + col] = hv;
                } else {
                    int bb = row >> 11, s = row & 2047;
                    int hh = col >> 6, d = col & 63;
                    CvT[(((size_t)bb * NH + hh) * HD + d) * SEQ + s] = hv;
                }
            }
        }
    }
}

// ---------------------------------------------------------------------------
// Output projection GEMM (+bias +fp32 residual), same BK=64 dbuf structure.
// (Unchanged for attribution.)
// ---------------------------------------------------------------------------
__global__ __launch_bounds__(256) void gemm_out(
    const ushort* __restrict__ A, const ushort* __restrict__ W,
    const float* __restrict__ bias, const float* __restrict__ resid,
    float* __restrict__ Cf, int M, int N, int K)
{
    __shared__ ushort As[2][BM * BKK];
    __shared__ ushort Ws[2][BM * BKK];
    const int tid = threadIdx.x;
    const int lane = tid & 63;
    const int wave = tid >> 6;
    const int wr = wave >> 1, wc = wave & 1;
    const int m0 = blockIdx.y * BM, n0 = blockIdx.x * BM;
    const int fr = lane & 15, quad = lane >> 4;
    const int r8 = lane >> 3, c8 = lane & 7;
    const int gc8 = c8 ^ r8;
    const int swf = fr & 7;

    const ushort* gA = A + (size_t)(m0 + wave * 32 + r8) * K + gc8 * 8;
    const ushort* gW = W + (size_t)(n0 + wave * 32 + r8) * K + gc8 * 8;
    const int ldso = (wave * 32) * BKK;

    f32x4 acc[4][4] = {};

    // prologue: stage tile 0 into buffer 0
#pragma unroll
    for (int t = 0; t < 4; ++t) {
        gl_lds16(gA + (size_t)t * 8 * K, &As[0][ldso + t * 8 * BKK]);
        gl_lds16(gW + (size_t)t * 8 * K, &Ws[0][ldso + t * 8 * BKK]);
    }
    __syncthreads();

    for (int k0 = 0; k0 < K; k0 += BKK) {
        const int cur = (k0 >> 6) & 1;
        if (k0 + BKK < K) {
            const int nxt = cur ^ 1;
#pragma unroll
            for (int t = 0; t < 4; ++t) {
                gl_lds16(gA + (size_t)t * 8 * K + k0 + BKK, &As[nxt][ldso + t * 8 * BKK]);
                gl_lds16(gW + (size_t)t * 8 * K + k0 + BKK, &Ws[nxt][ldso + t * 8 * BKK]);
            }
        }
#pragma unroll
        for (int kh = 0; kh < 2; ++kh) {
            bf16x8 af[4], bf[4];
            const int co = ((kh * 4 + quad) ^ swf) * 8;
#pragma unroll
            for (int i = 0; i < 4; ++i) {
                af[i] = *(const bf16x8*)&As[cur][(wr * 64 + i * 16 + fr) * BKK + co];
                bf[i] = *(const bf16x8*)&Ws[cur][(wc * 64 + i * 16 + fr) * BKK + co];
            }
#pragma unroll
            for (int i = 0; i < 4; ++i)
#pragma unroll
                for (int j = 0; j < 4; ++j)
                    acc[i][j] = __builtin_amdgcn_mfma_f32_16x16x32_bf16(af[i], bf[j], acc[i][j], 0, 0, 0);
        }
        __syncthreads();
    }

#pragma unroll
    for (int j = 0; j < 4; ++j) {
        int col = n0 + wc * 64 + j * 16 + fr;
        float bvl = bias[col];
#pragma unroll
        for (int i = 0; i < 4; ++i) {
#pragma unroll
            for (int r = 0; r < 4; ++r) {
                int row = m0 + wr * 64 + i * 16 + quad * 4 + r;
                Cf[(size_t)row * N + col] =
                    acc[i][j][r] + bvl + resid[(size_t)row * N + col];
            }
        }
    }
}

// ---------------------------------------------------------------------------
// MFMA flash attention, S^T formulation, 128 q-rows per block (2 strips per
// wave). K/V LDS double-buffered, one barrier per kb. Paired q-tiles
// (qt, 15-qt) per block. Phase-boundary prefetch (round-11 verified, +3us):
// phase 0's last iteration restages kb=0 into buf[0] for phase 1, which
// skips its serial prologue entirely.
//  - XCD-aware 1D grid: 8 bx-blocks sharing one (b,h) K/V stream -> same XCD.
//  - raw v_exp_f32 inline asm; v_cvt_pk_bf16_f32 P-pack; setprio(1) on MFMA.
// ---------------------------------------------------------------------------
#define PSP 72
__global__ __launch_bounds__(256, 3) void flash_mfma(
    const ushort* __restrict__ Q, const ushort* __restrict__ K,
    const ushort* __restrict__ VtG, const float* __restrict__ mask,
    ushort* __restrict__ O)
{
    const int id = blockIdx.x;
    const int bx = id >> 6;          // q-tile pair selector 0..7
    const int hb = id & 63;          // xcd = hb % 8 under round-robin
    const int h = hb & 15, b = hb >> 4;
    __shared__ ushort Ks[2][64 * 64];    // [key][d], swizzled 16B chunks
    __shared__ ushort Vt[2][64 * 64];    // [d][key], swizzled 16B chunks
    __shared__ ushort Ps[128 * PSP];     // [q][key], wave-private strips
    const int tid = threadIdx.x;
    const int lane = tid & 63, wave = tid >> 6;
    const int fr = lane & 15, quad = lane >> 4;
    const int srow = tid >> 3;
    const int sc8 = tid & 7;
    const int g8 = sc8 ^ (srow & 7);
    const int swf = fr & 7;

    const ushort* gK0 = K + (size_t)(b * SEQ) * D + h * HD + (size_t)srow * D + g8 * 8;
    const ushort* gK1 = gK0 + (size_t)32 * D;
    const ushort* gV0 = VtG + ((size_t)(b * NH + h) * HD + srow) * SEQ + g8 * 8;
    const ushort* gV1 = gV0 + (size_t)32 * SEQ;
    const float* mrow = mask + (size_t)b * SEQ;
    const float SCALE2 = 0.125f * LOG2E;
    const float MASKC = -10000.0f * LOG2E;

    for (int phase = 0; phase < 2; ++phase) {
        const int qt = phase ? (15 - bx) : bx;      // 128-row q tile
        const int q0 = qt * 128;
        // Q B-fragments for both strips, straight from global
        bf16x8 qf[2][2];
#pragma unroll
        for (int s = 0; s < 2; ++s) {
            const ushort* qptr = Q + ((size_t)(b * SEQ + q0 + s * 64 + wave * 16 + fr)) * D
                                   + h * HD + quad * 8;
            qf[s][0] = *(const bf16x8*)(qptr);
            qf[s][1] = *(const bf16x8*)(qptr + 32);
        }

        f32x4 oacc[2][4] = {};
        float lsum[2][4] = {};
        const int nkb = 2 * qt + 2;

        // prologue staging only at block start; phase 1's kb=0 buffer was
        // prefetched during phase 0's last iteration (published by its
        // end-of-iter __syncthreads).
        if (phase == 0) {
            gl_lds16(gK0, &Ks[0][wave * 512]);
            gl_lds16(gK1, &Ks[0][2048 + wave * 512]);
            gl_lds16(gV0, &Vt[0][wave * 512]);
            gl_lds16(gV1, &Vt[0][2048 + wave * 512]);
            __syncthreads();
        }

        for (int kb = 0; kb < nkb; ++kb) {
            const int cur = kb & 1;
            const bool last = (kb + 1 == nkb);
            if (!last || phase == 0) {
                // normal prefetch of kb+1; on phase 0's last iter, restage
                // kb=0 for phase 1 (nxt = nkb&1 = 0 since nkb even).
                const int nxt = cur ^ 1;
                const int kbn = last ? 0 : kb + 1;
                gl_lds16(gK0 + (size_t)kbn * 64 * D, &Ks[nxt][wave * 512]);
                gl_lds16(gK1 + (size_t)kbn * 64 * D, &Ks[nxt][2048 + wave * 512]);
                gl_lds16(gV0 + kbn * 64, &Vt[nxt][wave * 512]);
                gl_lds16(gV1 + kbn * 64, &Vt[nxt][2048 + wave * 512]);
            }
            f32x4 mv[4];
#pragma unroll
            for (int jt = 0; jt < 4; ++jt)
                mv[jt] = ((const f32x4*)(mrow + kb * 64))[jt * 4 + quad];

            const bool s0act = (kb <= 2 * qt);      // strip0 active (wave-uniform)

            // ---- S^T = K·Q^T for both strips (K frags shared) ----
            f32x4 sacc[2][4] = {};
            __builtin_amdgcn_s_setprio(1);
#pragma unroll
            for (int jt = 0; jt < 4; ++jt) {
                const int rb = (jt * 16 + fr) * 64;
                bf16x8 kf0 = *(const bf16x8*)&Ks[cur][rb + ((quad) ^ swf) * 8];
                bf16x8 kf1 = *(const bf16x8*)&Ks[cur][rb + ((4 + quad) ^ swf) * 8];
                sacc[0][jt] = __builtin_amdgcn_mfma_f32_16x16x32_bf16(kf0, qf[0][0], sacc[0][jt], 0, 0, 0);
                sacc[0][jt] = __builtin_amdgcn_mfma_f32_16x16x32_bf16(kf1, qf[0][1], sacc[0][jt], 0, 0, 0);
                sacc[1][jt] = __builtin_amdgcn_mfma_f32_16x16x32_bf16(kf0, qf[1][0], sacc[1][jt], 0, 0, 0);
                sacc[1][jt] = __builtin_amdgcn_mfma_f32_16x16x32_bf16(kf1, qf[1][1], sacc[1][jt], 0, 0, 0);
            }
            __builtin_amdgcn_s_setprio(0);

            // ---- softmax (fixed-max, raw v_exp_f32, cvt_pk bf16 P) ----
            float padd[4][4];
#pragma unroll
            for (int jt = 0; jt < 4; ++jt)
#pragma unroll
                for (int r = 0; r < 4; ++r)
                    padd[jt][r] = fmaf(mv[jt][r], -MASKC, MASKC);
            const int ql = wave * 16 + fr;
#pragma unroll
            for (int s = 0; s < 2; ++s) {
                if (s == 0 && !s0act) continue;
                const bool diag = (kb == 2 * qt + s);
#pragma unroll
                for (int jt = 0; jt < 4; ++jt) {
                    float p[4];
#pragma unroll
                    for (int r = 0; r < 4; ++r) {
                        float v = fmaf(sacc[s][jt][r], SCALE2, padd[jt][r]);
                        if (diag) {
                            int keyl = jt * 16 + quad * 4 + r;
                            v = (keyl > ql) ? -1e30f : v;
                        }
                        float e = exp2_raw(v);
                        p[r] = e;
                        lsum[s][r] += e;
                    }
                    uint w0, w1;
                    asm("v_cvt_pk_bf16_f32 %0, %1, %2" : "=v"(w0) : "v"(p[0]), "v"(p[1]));
                    asm("v_cvt_pk_bf16_f32 %0, %1, %2" : "=v"(w1) : "v"(p[2]), "v"(p[3]));
                    union { uint2 u; ushort4 us; } pu;
                    pu.u.x = w0; pu.u.y = w1;
                    *(ushort4*)&Ps[(s * 64 + wave * 16 + fr) * PSP + jt * 16 + quad * 4] = pu.us;
                }
            }
            // Ps strips are wave-private: no barrier needed.

            // ---- O += P·V (V frags shared across strips) ----
            bf16x8 pa[2][2];
#pragma unroll
            for (int s = 0; s < 2; ++s) {
                pa[s][0] = *(const bf16x8*)&Ps[(s * 64 + wave * 16 + fr) * PSP + quad * 8];
                pa[s][1] = *(const bf16x8*)&Ps[(s * 64 + wave * 16 + fr) * PSP + 32 + quad * 8];
            }
            __builtin_amdgcn_s_setprio(1);
#pragma unroll
            for (int dt = 0; dt < 4; ++dt) {
                const int rb = (dt * 16 + fr) * 64;
                bf16x8 vf0 = *(const bf16x8*)&Vt[cur][rb + ((quad) ^ swf) * 8];
                bf16x8 vf1 = *(const bf16x8*)&Vt[cur][rb + ((4 + quad) ^ swf) * 8];
                if (s0act) {
                    oacc[0][dt] = __builtin_amdgcn_mfma_f32_16x16x32_bf16(pa[0][0], vf0, oacc[0][dt], 0, 0, 0);
                    oacc[0][dt] = __builtin_amdgcn_mfma_f32_16x16x32_bf16(pa[0][1], vf1, oacc[0][dt], 0, 0, 0);
                }
                oacc[1][dt] = __builtin_amdgcn_mfma_f32_16x16x32_bf16(pa[1][0], vf0, oacc[1][dt], 0, 0, 0);
                oacc[1][dt] = __builtin_amdgcn_mfma_f32_16x16x32_bf16(pa[1][1], vf1, oacc[1][dt], 0, 0, 0);
            }
            __builtin_amdgcn_s_setprio(0);
            __syncthreads();   // drains prefetch vmcnt + all LDS reads of buf[cur]
        }

        // ---- finalize both strips ----
#pragma unroll
        for (int s = 0; s < 2; ++s) {
            float lt = (lsum[s][0] + lsum[s][1]) + (lsum[s][2] + lsum[s][3]);
            lt += __shfl_xor(lt, 16, 64);
            lt += __shfl_xor(lt, 32, 64);
            float linv[4];
#pragma unroll
            for (int r = 0; r < 4; ++r)
                linv[r] = 1.0f / __shfl(lt, quad * 4 + r, 64);
#pragma unroll
            for (int dt = 0; dt < 4; ++dt)
#pragma unroll
                for (int r = 0; r < 4; ++r) {
                    int q = q0 + s * 64 + wave * 16 + quad * 4 + r;
                    O[((size_t)(b * SEQ + q)) * D + h * HD + dt * 16 + fr] =
                        f2bf(oacc[s][dt][r] * linv[r]);
                }
        }
    }
}

// ---------------------------------------------------------------------------
extern "C" void kernel_launch(void* const* d_in, const int* in_sizes, int n_in,
                              void* d_out, int out_size, void* d_ws, size_t ws_size,
                              hipStream_t stream)
{
    const float* x     = (const float*)d_in[0];
    const float* amask = (const float*)d_in[1];
    const float* Wq    = (const float*)d_in[2];
    const float* bq    = (const float*)d_in[3];
    const float* Wk    = (const float*)d_in[4];
    const float* bk    = (const float*)d_in[5];
    const float* Wv    = (const float*)d_in[6];
    const float* bv    = (const float*)d_in[7];
    const float* Wo    = (const float*)d_in[8];
    const float* bo    = (const float*)d_in[9];
    const float* gamma = (const float*)d_in[10];
    const float* beta  = (const float*)d_in[11];
    float* out = (float*)d_out;

    const size_t MROWS = (size_t)BATCH * SEQ;  // 8192
    const size_t MB = 1024 * 1024;
    char* ws = (char*)d_ws;
    ushort* Qb    = (ushort*)(ws);             // 16 MB bf16 [B,S,D]
    ushort* Kb    = (ushort*)(ws + 16 * MB);   // 16 MB [B,S,D]
    ushort* Vtb   = (ushort*)(ws + 32 * MB);   // 16 MB [B,H,D,S]
    ushort* xn_bf = (ushort*)(ws + 48 * MB);   // 16 MB (reused as attn_bf)
    ushort* Wq_bf = (ushort*)(ws + 64 * MB);   // Wq,Wk,Wv,Wo contiguous
    ushort* Wo_bf = (ushort*)(ws + 70 * MB);
    ushort* attn_bf = xn_bf;

    // fused LN (1 wave/row, 2048 blocks) + weight-convert (4096 blocks)
    prep<<<dim3((unsigned)(MROWS / 4 + 4096)), 256, 0, stream>>>(
        x, gamma, beta, xn_bf, Wq, Wk, Wv, Wo, Wq_bf);

    gemm_qkv<<<dim3(1536), 256, 0, stream>>>(xn_bf, Wq_bf, bq, bk, bv,
                                             Qb, Kb, Vtb, (int)MROWS, D);

    flash_mfma<<<dim3(512), 256, 0, stream>>>(Qb, Kb, Vtb, amask, attn_bf);

    gemm_out<<<dim3(8, 64), 256, 0, stream>>>(attn_bf, Wo_bf, bo, x, out,
                                              (int)MROWS, D, D);
}